// Round 1
// baseline (659.879 us; speedup 1.0000x reference)
//
#include <hip/hip_runtime.h>
#include <math.h>

#define NN 8192
#define DD 128
#define THRESH 0.15f

#define ROWS 16      // rows per block
#define CTILE 1024   // columns per tile
#define KCH 16       // k-chunk staged in LDS
#define NTHREADS 256

// ---------------- normalize rows of x and store transposed: xT[k][j] ----------------
__global__ __launch_bounds__(256) void norm_transpose(const float* __restrict__ x,
                                                      float* __restrict__ xT) {
    __shared__ float T[DD][64];           // [k][row-in-tile]
    const int t = threadIdx.x;
    const int i0 = blockIdx.x * 64;
    const int r = t >> 2;                 // 0..63 row within tile
    const int q = t & 3;                  // quarter of D
    const float* xr = x + (size_t)(i0 + r) * DD + q * 32;
    float vals[32];
    float ss = 0.f;
#pragma unroll
    for (int m = 0; m < 8; ++m) {
        float4 v = reinterpret_cast<const float4*>(xr)[m];
        vals[m*4+0]=v.x; vals[m*4+1]=v.y; vals[m*4+2]=v.z; vals[m*4+3]=v.w;
        ss += v.x*v.x + v.y*v.y + v.z*v.z + v.w*v.w;
    }
    // combine the 4 lanes of this row
    ss += __shfl_xor(ss, 1);
    ss += __shfl_xor(ss, 2);
    float nrm = fmaxf(sqrtf(ss), 1e-12f);
#pragma unroll
    for (int m = 0; m < 32; ++m)
        T[q*32+m][r] = vals[m] / nrm;     // true divide to match reference rounding
    __syncthreads();
    // write out xT[k][i0 .. i0+63], coalesced float4
#pragma unroll
    for (int m = 0; m < 8; ++m) {
        int idx = t + m*256;              // float4 index over [128][64] = 2048
        int k  = idx >> 4;                // 16 float4 per k
        int rq = idx & 15;
        float4 v;
        v.x = T[k][rq*4+0]; v.y = T[k][rq*4+1];
        v.z = T[k][rq*4+2]; v.w = T[k][rq*4+3];
        reinterpret_cast<float4*>(xT + (size_t)k * NN + i0)[rq] = v;
    }
}

// insert candidate (v,j) into sorted-desc top-4 (tie: smaller index wins)
__device__ __forceinline__ void ins4(float v, int j, float* tv, int* ti) {
    bool b3 = (v > tv[3]) | ((v == tv[3]) & (j < ti[3]));
    if (b3) {
        bool b0 = (v > tv[0]) | ((v == tv[0]) & (j < ti[0]));
        bool b1 = (v > tv[1]) | ((v == tv[1]) & (j < ti[1]));
        bool b2 = (v > tv[2]) | ((v == tv[2]) & (j < ti[2]));
        if (b0)      { tv[3]=tv[2];ti[3]=ti[2]; tv[2]=tv[1];ti[2]=ti[1]; tv[1]=tv[0];ti[1]=ti[0]; tv[0]=v;ti[0]=j; }
        else if (b1) { tv[3]=tv[2];ti[3]=ti[2]; tv[2]=tv[1];ti[2]=ti[1]; tv[1]=v;ti[1]=j; }
        else if (b2) { tv[3]=tv[2];ti[3]=ti[2]; tv[2]=v;ti[2]=j; }
        else         { tv[3]=v;ti[3]=j; }
    }
}

__global__ __launch_bounds__(256, 2) void graph_build(const float* __restrict__ xT,
                                                      float* __restrict__ adj,
                                                      float* __restrict__ ew) {
    __shared__ float colT[KCH][CTILE];    // 64 KB, k-major column tile
    __shared__ float rowT[DD][ROWS];      // 8 KB,  k-major row tile (full K)
    const int t  = threadIdx.x;
    const int i0 = blockIdx.x * ROWS;
    const int tr = t >> 7;                // row group 0..1  (8 rows each)
    const int tc = t & 127;               // col group 0..127 (8 cols each)

    // stage this block's 16 rows, k-major: rowT[k][r] = xT[k][i0+r]
    for (int idx = t; idx < DD*ROWS/4; idx += NTHREADS) {   // 512 float4
        int k  = idx >> 2;
        int rq = idx & 3;
        float4 v = reinterpret_cast<const float4*>(xT + (size_t)k*NN + i0)[rq];
        rowT[k][rq*4+0]=v.x; rowT[k][rq*4+1]=v.y; rowT[k][rq*4+2]=v.z; rowT[k][rq*4+3]=v.w;
    }

    float tv[8][4]; int ti[8][4];
#pragma unroll
    for (int r = 0; r < 8; ++r)
#pragma unroll
        for (int s = 0; s < 4; ++s) { tv[r][s] = -1e30f; ti[r][s] = 0x7fffffff; }

    const float4 z4 = make_float4(0.f, 0.f, 0.f, 0.f);

    for (int ct = 0; ct < NN/CTILE; ++ct) {
        float acc[8][8];
#pragma unroll
        for (int r = 0; r < 8; ++r)
#pragma unroll
            for (int c = 0; c < 8; ++c) acc[r][c] = 0.f;

        for (int kc = 0; kc < DD/KCH; ++kc) {
            __syncthreads();              // previous colT consumers done
            // stage colT[kk][j] = xT[kc*KCH+kk][ct*CTILE + j]  (row-contiguous copy)
#pragma unroll
            for (int m = 0; m < (KCH*CTILE/4)/NTHREADS; ++m) {  // 16
                int idx = t + m*NTHREADS;
                int kk = idx >> 8;        // CTILE/4 = 256 float4 per kk
                int jq = idx & 255;
                float4 v = reinterpret_cast<const float4*>(
                    xT + (size_t)(kc*KCH+kk)*NN + (size_t)ct*CTILE)[jq];
                reinterpret_cast<float4*>(&colT[kk][0])[jq] = v;
            }
            __syncthreads();
#pragma unroll
            for (int kk = 0; kk < KCH; ++kk) {
                const float4 a0 = *reinterpret_cast<const float4*>(&rowT[kc*KCH+kk][tr*8]);
                const float4 a1 = *reinterpret_cast<const float4*>(&rowT[kc*KCH+kk][tr*8+4]);
                const float4 b0 = *reinterpret_cast<const float4*>(&colT[kk][tc*8]);
                const float4 b1 = *reinterpret_cast<const float4*>(&colT[kk][tc*8+4]);
                const float av[8] = {a0.x,a0.y,a0.z,a0.w,a1.x,a1.y,a1.z,a1.w};
                const float bv[8] = {b0.x,b0.y,b0.z,b0.w,b1.x,b1.y,b1.z,b1.w};
#pragma unroll
                for (int r = 0; r < 8; ++r)
#pragma unroll
                    for (int c = 0; c < 8; ++c)
                        acc[r][c] += av[r]*bv[c];
            }
        }

        // zero-fill this block's rows for this column tile (overlaps next tile's compute)
#pragma unroll
        for (int m = 0; m < 16; ++m) {
            int idx = t + m*NTHREADS;     // over ROWS*CTILE/4 = 4096 float4
            int rr = idx >> 8;
            int cq = idx & 255;
            size_t off4 = (size_t)(i0+rr) * (NN/4) + (size_t)ct * (CTILE/4) + cq;
            reinterpret_cast<float4*>(adj)[off4] = z4;
            reinterpret_cast<float4*>(ew)[off4]  = z4;
        }

        // fold this tile's 8x8 results into per-thread running top-4
#pragma unroll
        for (int r = 0; r < 8; ++r) {
            const int ig = i0 + tr*8 + r;
#pragma unroll
            for (int c = 0; c < 8; ++c) {
                int j = ct*CTILE + tc*8 + c;
                if (j != ig) ins4(acc[r][c], j, tv[r], ti[r]);
            }
        }
    }

    // ---- merge per-thread top-4 lists into per-row global top-4 ----
    __syncthreads();   // also drains all zero-fill stores (vmcnt(0) before barrier)
    float* smv = reinterpret_cast<float*>(&colT[0][0]);          // [16][2][4] vals
    int*   smi = reinterpret_cast<int*>((char*)&colT[0][0] + 16*2*4*sizeof(float));
    const int lane = t & 63;
    const int wv   = (t >> 6) & 1;        // which half of the tc range within this tr

#pragma unroll
    for (int r = 0; r < 8; ++r) {
        float mv[4]; int mi[4];
#pragma unroll
        for (int s = 0; s < 4; ++s) { mv[s]=tv[r][s]; mi[s]=ti[r][s]; }
#pragma unroll
        for (int d = 1; d < 64; d <<= 1) {
            float pv0=__shfl_xor(mv[0],d), pv1=__shfl_xor(mv[1],d),
                  pv2=__shfl_xor(mv[2],d), pv3=__shfl_xor(mv[3],d);
            int   pi0=__shfl_xor(mi[0],d), pi1=__shfl_xor(mi[1],d),
                  pi2=__shfl_xor(mi[2],d), pi3=__shfl_xor(mi[3],d);
            ins4(pv0,pi0,mv,mi); ins4(pv1,pi1,mv,mi);
            ins4(pv2,pi2,mv,mi); ins4(pv3,pi3,mv,mi);
        }
        if (lane == 0) {
            int row = tr*8 + r;
#pragma unroll
            for (int s = 0; s < 4; ++s) {
                smv[row*8 + wv*4 + s] = mv[s];
                smi[row*8 + wv*4 + s] = mi[s];
            }
        }
    }
    __syncthreads();
    if (t < ROWS) {
        float mv[4]; int mi[4];
#pragma unroll
        for (int s = 0; s < 4; ++s) { mv[s] = smv[t*8+s]; mi[s] = smi[t*8+s]; }
#pragma unroll
        for (int s = 0; s < 4; ++s) ins4(smv[t*8+4+s], smi[t*8+4+s], mv, mi);
        const int ig = i0 + t;
#pragma unroll
        for (int s = 0; s < 4; ++s) {
            if (mv[s] > THRESH) {
                adj[(size_t)ig*NN + mi[s]] = 1.0f;
                ew [(size_t)ig*NN + mi[s]] = mv[s];
            }
        }
    }
}

extern "C" void kernel_launch(void* const* d_in, const int* in_sizes, int n_in,
                              void* d_out, int out_size, void* d_ws, size_t ws_size,
                              hipStream_t stream) {
    const float* x = (const float*)d_in[0];
    float* xT  = (float*)d_ws;                    // 128*8192*4 = 4 MB scratch
    float* adj = (float*)d_out;
    float* ew  = adj + (size_t)NN*NN;
    hipLaunchKernelGGL(norm_transpose, dim3(NN/64), dim3(256), 0, stream, x, xT);
    hipLaunchKernelGGL(graph_build, dim3(NN/ROWS), dim3(256), 0, stream, xT, adj, ew);
}

// Round 2
// 319.228 us; speedup vs baseline: 2.0671x; 2.0671x over previous
//
#include <hip/hip_runtime.h>
#include <math.h>

#define NN 8192
#define DD 128
#define THRESH 0.15f
#define BM 16

typedef __attribute__((ext_vector_type(8))) short short8;
typedef __attribute__((ext_vector_type(4))) float f32x4;

// round-to-nearest-even f32 -> bf16 bits
__device__ __forceinline__ unsigned short f2bf(float f) {
    unsigned int u = __float_as_uint(f);
    return (unsigned short)((u + 0x7fffu + ((u >> 16) & 1u)) >> 16);
}

// insert (v,j) into sorted-desc top-8 (tie: smaller index first)
__device__ __forceinline__ void ins8(float v, int j, float* tv, int* ti) {
    bool in = (v > tv[7]) | ((v == tv[7]) & (j < ti[7]));
    if (!in) return;
#pragma unroll
    for (int s = 7; s >= 1; --s) {
        bool up = (v > tv[s - 1]) | ((v == tv[s - 1]) & (j < ti[s - 1]));
        tv[s] = up ? tv[s - 1] : v;
        ti[s] = up ? ti[s - 1] : j;
        if (!up) return;
    }
    tv[0] = v; ti[0] = j;
}

// ------- K1: normalize rows, emit bf16 x-hat (row-major, k-contiguous) -------
__global__ __launch_bounds__(256) void norm_rows(const float* __restrict__ x,
                                                 unsigned int* __restrict__ xb) {
    const int t = threadIdx.x;
    const int lane = t & 63;
    const int i = blockIdx.x * 4 + (t >> 6);
    float2 v = reinterpret_cast<const float2*>(x + (size_t)i * DD)[lane];
    float ss = v.x * v.x + v.y * v.y;
#pragma unroll
    for (int d = 1; d < 64; d <<= 1) ss += __shfl_xor(ss, d);
    float inv = 1.0f / fmaxf(sqrtf(ss), 1e-12f);
    unsigned short b0 = f2bf(v.x * inv), b1 = f2bf(v.y * inv);
    xb[(size_t)i * 64 + lane] = ((unsigned int)b1 << 16) | b0;
}

// ------- K2: MFMA sim sweep + per-row approx top-8 + zero-fill outputs -------
__global__ __launch_bounds__(256) void simtopk(const unsigned int* __restrict__ xbw,
                                               int* __restrict__ cidx,
                                               float* __restrict__ adj,
                                               float* __restrict__ ew) {
    __shared__ float smv[BM][4][8];
    __shared__ int   smi[BM][4][8];
    const int t    = threadIdx.x;
    const int lane = t & 63;
    const int w    = t >> 6;              // wave 0..3
    const int i0   = blockIdx.x * BM;
    const int l15  = lane & 15;
    const int lh   = lane >> 4;           // 0..3
    const int i    = i0 + l15;            // this lane's output row
    const short* xbs = reinterpret_cast<const short*>(xbw);

    // B-operand frags (the 16 block rows), lane holds xr[i0+l15][kc*32 + lh*8 .. +7]
    short8 rf[4];
#pragma unroll
    for (int kc = 0; kc < 4; ++kc)
        rf[kc] = *reinterpret_cast<const short8*>(
            xbs + (size_t)(i0 + l15) * DD + kc * 32 + lh * 8);

    float tv[8]; int ti[8];
#pragma unroll
    for (int s = 0; s < 8; ++s) { tv[s] = -1e30f; ti[s] = 0x7fffffff; }

    const f32x4 z4 = {0.f, 0.f, 0.f, 0.f};
    const size_t zb = (size_t)(i0 + w * 4) * (NN / 4);  // wave's zero panel base (f4 idx)

    for (int jc = 0; jc < 128; ++jc) {
        const int j0 = w * 2048 + jc * 16;              // wave's 16-col chunk
        f32x4 acc = {0.f, 0.f, 0.f, 0.f};
#pragma unroll
        for (int kc = 0; kc < 4; ++kc) {
            short8 cf = *reinterpret_cast<const short8*>(
                xbs + (size_t)(j0 + l15) * DD + kc * 32 + lh * 8);
            acc = __builtin_amdgcn_mfma_f32_16x16x32_bf16(cf, rf[kc], acc, 0, 0, 0);
        }
        // interleaved zero-fill: 2 nontemporal float4 per lane per chunk
#pragma unroll
        for (int s = 0; s < 2; ++s) {
            int u = jc * 128 + s * 64 + lane;           // 0..16383, wave-uniform branch
            float* base = (u < 8192) ? adj : ew;
            int p = u & 8191;
            __builtin_nontemporal_store(z4,
                reinterpret_cast<f32x4*>(base) + zb + (size_t)(p >> 11) * (NN / 4) + (p & 2047));
        }
        // fold this chunk's 4 candidates (lane holds row i, cands j0+lh*4+r)
#pragma unroll
        for (int r = 0; r < 4; ++r) {
            int j = j0 + lh * 4 + r;
            if (j != i) ins8(acc[r], j, tv, ti);
        }
    }

    // merge the 4 lane-groups sharing row i (lanes l, l+16, l+32, l+48)
#pragma unroll
    for (int d = 16; d < 64; d <<= 1) {
        float ov[8]; int oi[8];
#pragma unroll
        for (int s = 0; s < 8; ++s) { ov[s] = __shfl_xor(tv[s], d); oi[s] = __shfl_xor(ti[s], d); }
#pragma unroll
        for (int s = 0; s < 8; ++s) ins8(ov[s], oi[s], tv, ti);
    }
    if (lane < 16) {
#pragma unroll
        for (int s = 0; s < 8; ++s) { smv[lane][w][s] = tv[s]; smi[lane][w][s] = ti[s]; }
    }
    __syncthreads();
    // cross-wave merge + emit candidate indices
    if (t < BM) {
        float mv[8]; int mi[8];
#pragma unroll
        for (int s = 0; s < 8; ++s) { mv[s] = smv[t][0][s]; mi[s] = smi[t][0][s]; }
#pragma unroll
        for (int ww = 1; ww < 4; ++ww)
#pragma unroll
            for (int s = 0; s < 8; ++s) ins8(smv[t][ww][s], smi[t][ww][s], mv, mi);
#pragma unroll
        for (int s = 0; s < 8; ++s) cidx[(size_t)(i0 + t) * 8 + s] = mi[s];
    }
}

// ------- K3: exact fp32 re-rank of 8 candidates, scatter adj/ew -------
__global__ __launch_bounds__(256) void rerank(const float* __restrict__ x,
                                              const int* __restrict__ cidx,
                                              float* __restrict__ adj,
                                              float* __restrict__ ew) {
    const int t = threadIdx.x;
    const int lane = t & 63;
    const int i = blockIdx.x * 4 + (t >> 6);
    float2 a = reinterpret_cast<const float2*>(x + (size_t)i * DD)[lane];
    float ss = a.x * a.x + a.y * a.y;
#pragma unroll
    for (int d = 1; d < 64; d <<= 1) ss += __shfl_xor(ss, d);
    float ni = fmaxf(sqrtf(ss), 1e-12f);

    int myc = (lane < 8) ? cidx[(size_t)i * 8 + lane] : 0;
    float sv[8]; int jv[8];
#pragma unroll
    for (int c = 0; c < 8; ++c) {
        int j = __shfl(myc, c);
        float2 b = reinterpret_cast<const float2*>(x + (size_t)j * DD)[lane];
        float dp = a.x * b.x + a.y * b.y;
        float sb = b.x * b.x + b.y * b.y;
#pragma unroll
        for (int d = 1; d < 64; d <<= 1) { dp += __shfl_xor(dp, d); sb += __shfl_xor(sb, d); }
        float nj = fmaxf(sqrtf(sb), 1e-12f);
        sv[c] = dp / (ni * nj);
        jv[c] = j;
    }
    if (lane == 0) {
#pragma unroll
        for (int c = 0; c < 8; ++c) {
            int beats = 0;
#pragma unroll
            for (int c2 = 0; c2 < 8; ++c2)
                beats += ((sv[c2] > sv[c]) | ((sv[c2] == sv[c]) & (jv[c2] < jv[c]))) ? 1 : 0;
            if (beats < 4 && sv[c] > THRESH) {
                adj[(size_t)i * NN + jv[c]] = 1.0f;
                ew [(size_t)i * NN + jv[c]] = sv[c];
            }
        }
    }
}

extern "C" void kernel_launch(void* const* d_in, const int* in_sizes, int n_in,
                              void* d_out, int out_size, void* d_ws, size_t ws_size,
                              hipStream_t stream) {
    const float* x = (const float*)d_in[0];
    unsigned int* xb = (unsigned int*)d_ws;                         // 2 MB bf16 x-hat
    int* cidx = (int*)((char*)d_ws + (2u << 20));                   // 256 KB candidates
    float* adj = (float*)d_out;
    float* ew  = adj + (size_t)NN * NN;
    hipLaunchKernelGGL(norm_rows, dim3(NN / 4), dim3(256), 0, stream, x, xb);
    hipLaunchKernelGGL(simtopk,  dim3(NN / BM), dim3(256), 0, stream, xb, cidx, adj, ew);
    hipLaunchKernelGGL(rerank,   dim3(NN / 4), dim3(256), 0, stream, x, cidx, adj, ew);
}